// Round 11
// baseline (163.695 us; speedup 1.0000x reference)
//
#include <hip/hip_runtime.h>
#include <hip/hip_bf16.h>

// Capsule dynamic routing, round 21 = R17 (155.4 us, passing) + cvt_x folded
// into wsum0 via idempotent duplicate writes. Persistent-kernel path (R18-R20)
// is CLOSED: three barrier variants all gave moderate garbage with verbatim
// phase bodies; root cause undetermined (suspect cross-XCD visibility).
//
// Fold mechanics: each wsum0 block (chunk, ny) converts its chunk's x-slab
// (16 j x 64 b x 16 d) f32->bf16 and stores to global xt BEFORE its MFMA
// loop. The 8 ny-blocks per chunk write IDENTICAL bytes (cvt_pk_bf16 is
// deterministic) -> cross-block write overlap is harmless; own-block reads
// are ordered by one __syncthreads (vmcnt drain wanted here); fused passes
// read xt in later dispatches (stream-ordered). 7 -> 6 dispatches.
//
// Pipeline: [wsum0+cvtx+cvtW; reduce0] [fused; reduce] x2.
// x[64][2048][16] f32, W[32][2048][16][16] f32 -> v[64][32][16] f32.
// MFMA layouts (verified): 16x16x32 C/D col=lane&15,row=(lane>>4)*4+reg,
// A[m=lane&15][k=(lane>>4)*8+t]; 32x32x16 C/D col=lane&31,
// row=(reg&3)+8*(reg>>2)+4*(lane>>5), A/B [m|n=lane&31][k=(lane>>5)*8+t].

#define J_DIM 2048
#define NCH0 128           // wsum0 j-chunks (16 j each)
#define NCHF 256           // fused j-chunks (8 j each)

typedef __attribute__((ext_vector_type(8))) short bf16x8;
typedef __attribute__((ext_vector_type(4))) short bf16x4;
typedef __attribute__((ext_vector_type(4))) float f32x4;
typedef __attribute__((ext_vector_type(16))) float f32x16;

__device__ inline float bf2f(short s) {
    union { unsigned u; float f; } v; v.u = ((unsigned)(unsigned short)s) << 16;
    return v.f;
}
// packed f32x2 -> bf16x2 (RNE)
__device__ inline int cvt_pk_bf16(float lo, float hi) {
    int r;
    asm("v_cvt_pk_bf16_f32 %0, %1, %2" : "=v"(r) : "v"(lo), "v"(hi));
    return r;
}
// Barrier WITHOUT the vmcnt(0) drain (R16-validated; intra-block LDS only).
__device__ inline void lds_barrier() {
    __builtin_amdgcn_sched_barrier(0);
    asm volatile("s_waitcnt lgkmcnt(0)" ::: "memory");
    __builtin_amdgcn_sched_barrier(0);
    __builtin_amdgcn_s_barrier();
    __builtin_amdgcn_sched_barrier(0);
}

// Pass 0 + folded cvt_x: convert chunk's x-slab -> xt (idempotent), then
// read W f32 once (coalesced 1KB rows), convert+write Wt[j][n][256] bf16,
// accumulate UNSCALED uniform-c partials (1/32 applied in reduce0).
// grid(NCH0, 8) x 256 thr; wave = (chunk, n); 4 b-tiles in-wave.
__global__ __launch_bounds__(256)
void wsum0_cvt_k(const float* __restrict__ x, const float* __restrict__ W,
                 short* __restrict__ Wt, short* __restrict__ xt,
                 short* __restrict__ sp) {
    const int t = threadIdx.x, lane = t & 63, w = t >> 6;
    const int col = lane & 15, g = lane >> 4;
    const int n = blockIdx.y * 4 + w;
    const int chunk = blockIdx.x;

    // ---- folded cvt_x: this chunk's x slab f32 -> xt bf16 ----
    // r = b*16 + j_local (j fast): each thread reads 4 consecutive j-rows of
    // one b = 256 B contiguous from x; writes 4 x 32 B rows of xt.
    {
        const int r0 = t * 4;
        const int b0 = r0 >> 4, jl0 = r0 & 15;   // 4 consecutive j, same b
        const float4* s = (const float4*)(x + ((size_t)b0 * J_DIM + chunk * 16 + jl0) * 16);
#pragma unroll
        for (int rr = 0; rr < 4; ++rr) {
            float4 q0 = s[rr * 4 + 0], q1 = s[rr * 4 + 1];
            float4 q2 = s[rr * 4 + 2], q3 = s[rr * 4 + 3];
            int pk[8];
            pk[0] = cvt_pk_bf16(q0.x, q0.y); pk[1] = cvt_pk_bf16(q0.z, q0.w);
            pk[2] = cvt_pk_bf16(q1.x, q1.y); pk[3] = cvt_pk_bf16(q1.z, q1.w);
            pk[4] = cvt_pk_bf16(q2.x, q2.y); pk[5] = cvt_pk_bf16(q2.z, q2.w);
            pk[6] = cvt_pk_bf16(q3.x, q3.y); pk[7] = cvt_pk_bf16(q3.z, q3.w);
            short* d = xt + ((size_t)(chunk * 16 + jl0 + rr) * 64 + b0) * 16;
            *(bf16x8*)d = *(bf16x8*)pk;
            *(bf16x8*)(d + 8) = *(bf16x8*)&pk[4];
        }
    }
    // vmcnt drain + barrier: own-block xt stores complete before any lane
    // reads them below. (Other chunks' blocks write identical bytes.)
    __syncthreads();

    f32x4 acc[4];
#pragma unroll
    for (int bt = 0; bt < 4; ++bt) acc[bt] = (f32x4){0.f, 0.f, 0.f, 0.f};

#pragma unroll
    for (int jp = 0; jp < 8; ++jp) {
        const int jq = chunk * 16 + jp * 2 + (g >> 1);
        // lane's 8 f32 of W[n][jq] row; half-wave covers the full 1KB row
        const float4* wsrc = (const float4*)(W + ((size_t)n * J_DIM + jq) * 256 + col * 16 + (g & 1) * 8);
        float4 a = wsrc[0], b2 = wsrc[1];
        int pk[4];
        pk[0] = cvt_pk_bf16(a.x, a.y);   pk[1] = cvt_pk_bf16(a.z, a.w);
        pk[2] = cvt_pk_bf16(b2.x, b2.y); pk[3] = cvt_pk_bf16(b2.z, b2.w);
        bf16x8 af = *(bf16x8*)pk;
        *(bf16x8*)(Wt + ((size_t)jq * 32 + n) * 256 + col * 16 + (g & 1) * 8) = af;
#pragma unroll
        for (int bt = 0; bt < 4; ++bt) {
            const int b = bt * 16 + col;
            bf16x8 xr = *(const bf16x8*)(xt + ((size_t)jq * 64 + b) * 16 + (g & 1) * 8);
            acc[bt] = __builtin_amdgcn_mfma_f32_16x16x32_bf16(af, xr, acc[bt], 0, 0, 0);
        }
    }
#pragma unroll
    for (int bt = 0; bt < 4; ++bt) {
        int o[2] = { cvt_pk_bf16(acc[bt][0], acc[bt][1]),
                     cvt_pk_bf16(acc[bt][2], acc[bt][3]) };
        *(bf16x4*)(sp + (((size_t)chunk * 32 + n) * 64 + bt * 16 + col) * 16 + g * 4) = *(bf16x4*)o;
    }
}

// Fused routing pass (32x32x16 MFMA): sp[chunk][n][b][d] = sum_{j in chunk}
// softmax_n(v.u_hat) * u_hat for one 32-b half. grid(NCHF, 2) x 512 thr.
// wave w = n-group {4w..4w+3}; lane: b-col = lane&31, half h = lane>>5.
__global__ __launch_bounds__(512, 4)
void fused_pass_k(const short* __restrict__ Wt, const short* __restrict__ xt,
                  const float* __restrict__ vsumT, short* __restrict__ sp) {
    const int t = threadIdx.x, lane = t & 63, w = t >> 6;   // w 0..7: n-group
    const int bc = lane & 31, h = lane >> 5;
    const int chunk = blockIdx.x;          // 8-j chunk
    const int bh = blockIdx.y;             // b-half
    const int b = bh * 32 + bc;
    const int n0 = w * 4;

    // A-row role of this lane: m = lane&31 -> (pair-sub n, d)
    const int nsub = bc >> 4;              // 0: lo n of pair, 1: hi n
    const int ad = bc & 15;                // d of the A row

    __shared__ float psum[2][8][32];       // [parity][wave][b-col]

    // per-lane slice of vsumT[n0+q][b][d], d in {0..3}+4h and {8..11}+4h
    float4 vvA[4], vvB[4];
#pragma unroll
    for (int q = 0; q < 4; ++q) {
        const float* vp = vsumT + ((size_t)(n0 + q) * 64 + b) * 16;
        vvA[q] = *(const float4*)(vp + 4 * h);
        vvB[q] = *(const float4*)(vp + 8 + 4 * h);
    }

    const f32x16 z16 = {0.f,0.f,0.f,0.f,0.f,0.f,0.f,0.f,
                        0.f,0.f,0.f,0.f,0.f,0.f,0.f,0.f};
    f32x16 acc0 = z16, acc1 = z16;

#pragma unroll 1
    for (int jj = 0; jj < 8; ++jj) {
        const int j = chunk * 8 + jj;
        // B: x[b][j][k], k = h*8+t (full K=16, no masking)
        const bf16x8 xb = *(const bf16x8*)(xt + ((size_t)j * 64 + b) * 16 + h * 8);
        // A: rows = (n-pair, d); lane loads Wt[j][n0+2p+nsub][ad*16 + h*8]
        const bf16x8 af0 = *(const bf16x8*)(Wt + ((size_t)j * 32 + n0 + nsub) * 256 + ad * 16 + h * 8);
        const bf16x8 af1 = *(const bf16x8*)(Wt + ((size_t)j * 32 + n0 + 2 + nsub) * 256 + ad * 16 + h * 8);

        f32x16 u0 = __builtin_amdgcn_mfma_f32_32x32x16_bf16(af0, xb, z16, 0, 0, 0);
        f32x16 u1 = __builtin_amdgcn_mfma_f32_32x32x16_bf16(af1, xb, z16, 0, 0, 0);

        // logits: lane's half-dot over its 8 d's, then combine halves
        float lp0 = vvA[0].x*u0[0] + vvA[0].y*u0[1] + vvA[0].z*u0[2] + vvA[0].w*u0[3]
                  + vvB[0].x*u0[4] + vvB[0].y*u0[5] + vvB[0].z*u0[6] + vvB[0].w*u0[7];
        float lp1 = vvA[1].x*u0[8] + vvA[1].y*u0[9] + vvA[1].z*u0[10] + vvA[1].w*u0[11]
                  + vvB[1].x*u0[12] + vvB[1].y*u0[13] + vvB[1].z*u0[14] + vvB[1].w*u0[15];
        float lp2 = vvA[2].x*u1[0] + vvA[2].y*u1[1] + vvA[2].z*u1[2] + vvA[2].w*u1[3]
                  + vvB[2].x*u1[4] + vvB[2].y*u1[5] + vvB[2].z*u1[6] + vvB[2].w*u1[7];
        float lp3 = vvA[3].x*u1[8] + vvA[3].y*u1[9] + vvA[3].z*u1[10] + vvA[3].w*u1[11]
                  + vvB[3].x*u1[12] + vvB[3].y*u1[13] + vvB[3].z*u1[14] + vvB[3].w*u1[15];
        lp0 += __shfl_xor(lp0, 32);
        lp1 += __shfl_xor(lp1, 32);
        lp2 += __shfl_xor(lp2, 32);
        lp3 += __shfl_xor(lp3, 32);
        // no max-sub: |v|2<=0.5 (squash), |u|2<~8 => |logit|<=~4, f32-safe
        const float e0 = __expf(lp0), e1 = __expf(lp1);
        const float e2 = __expf(lp2), e3 = __expf(lp3);

        const int p = jj & 1;              // parity LDS buffer (WAR across j)
        if (h == 0) psum[p][w][bc] = e0 + e1 + e2 + e3;
        lds_barrier();
        float Z = 0.f;
#pragma unroll
        for (int ww = 0; ww < 8; ++ww) Z += psum[p][ww][bc];
        const float rz = __builtin_amdgcn_rcpf(Z);
        const float c0 = e0 * rz, c1 = e1 * rz, c2 = e2 * rz, c3 = e3 * rz;
#pragma unroll
        for (int r = 0; r < 16; ++r) {
            acc0[r] += (r < 8 ? c0 : c1) * u0[r];
            acc1[r] += (r < 8 ? c2 : c3) * u1[r];
        }
    }

    // epilogue: reg r -> (n, d): regs 0..3 d=4h.., 4..7 d=8+4h.., 8..15 hi n
#pragma unroll
    for (int pair = 0; pair < 2; ++pair) {
        const f32x16 a = pair ? acc1 : acc0;
        const int nb = n0 + 2 * pair;
        short* lo = sp + (((size_t)chunk * 32 + nb) * 64 + b) * 16;
        short* hi = sp + (((size_t)chunk * 32 + nb + 1) * 64 + b) * 16;
        int o[2];
        o[0] = cvt_pk_bf16(a[0], a[1]);  o[1] = cvt_pk_bf16(a[2], a[3]);
        *(bf16x4*)(lo + 4 * h) = *(bf16x4*)o;
        o[0] = cvt_pk_bf16(a[4], a[5]);  o[1] = cvt_pk_bf16(a[6], a[7]);
        *(bf16x4*)(lo + 8 + 4 * h) = *(bf16x4*)o;
        o[0] = cvt_pk_bf16(a[8], a[9]);  o[1] = cvt_pk_bf16(a[10], a[11]);
        *(bf16x4*)(hi + 4 * h) = *(bf16x4*)o;
        o[0] = cvt_pk_bf16(a[12], a[13]); o[1] = cvt_pk_bf16(a[14], a[15]);
        *(bf16x4*)(hi + 8 + 4 * h) = *(bf16x4*)o;
    }
}

// fold nch bf16 chunk partials, squash, update vsumT / write out. wave per (n,b).
// is_first: STORE vsum and apply the uniform-c 1/32 wsum0 does not pre-apply.
__global__ __launch_bounds__(256)
void reduce_k(const short* __restrict__ sp, float* __restrict__ vsumT,
              float* __restrict__ out, int nch, int is_first, int is_last) {
    const int t = threadIdx.x, lane = t & 63, w = t >> 6;
    const int q = blockIdx.x * 4 + w;       // 0..2047
    const int n = q >> 6, b = q & 63;
    const int d4 = lane & 3, ch = lane >> 2;   // ch 0..15

    float4 a = make_float4(0.f, 0.f, 0.f, 0.f);
    for (int m = 0; m < (nch >> 4); ++m) {
        bf16x4 v = *(const bf16x4*)(sp + (((size_t)(ch + 16 * m) * 32 + n) * 64 + b) * 16 + d4 * 4);
        a.x += bf2f(v[0]); a.y += bf2f(v[1]); a.z += bf2f(v[2]); a.w += bf2f(v[3]);
    }
#pragma unroll
    for (int mk = 4; mk <= 32; mk <<= 1) {
        a.x += __shfl_xor(a.x, mk); a.y += __shfl_xor(a.y, mk);
        a.z += __shfl_xor(a.z, mk); a.w += __shfl_xor(a.w, mk);
    }
    const float sc = is_first ? 0.03125f : 1.0f;   // uniform c = 1/32 (pass 0)
    a.x *= sc; a.y *= sc; a.z *= sc; a.w *= sc;
    float tt = a.x * a.x + a.y * a.y + a.z * a.z + a.w * a.w;
    tt += __shfl_xor(tt, 1);
    tt += __shfl_xor(tt, 2);
    float s2 = tt + 1e-7f;
    float scale = sqrtf(s2) / (1.0f + s2);

    if (lane < 4) {
        float4 v = make_float4(a.x * scale, a.y * scale, a.z * scale, a.w * scale);
        if (is_last) {
            *(float4*)(out + ((size_t)b * 32 + n) * 16 + d4 * 4) = v;   // [b][n][d]
        } else {
            float* p = vsumT + ((size_t)n * 64 + b) * 16 + d4 * 4;      // [n][b][d]
            if (is_first) {
                *(float4*)p = v;
            } else {
                float4 o = *(const float4*)p;
                *(float4*)p = make_float4(o.x + v.x, o.y + v.y, o.z + v.z, o.w + v.w);
            }
        }
    }
}

extern "C" void kernel_launch(void* const* d_in, const int* in_sizes, int n_in,
                              void* d_out, int out_size, void* d_ws, size_t ws_size,
                              hipStream_t stream) {
    const float* x = (const float*)d_in[0];   // [64,2048,16]
    const float* W = (const float*)d_in[1];   // [32,2048,16,16]
    float* out = (float*)d_out;               // [64,32,16]

    char* wsb = (char*)d_ws;
    short* Wt    = (short*)(wsb);                        // 33.5 MB [j][n][256]
    short* xt    = (short*)(wsb + 33556480);             // 4.2 MB [j][b][16]
    short* sp    = (short*)(wsb + 37750784);             // 16.78 MB [chunk<=256][n][b][d]
    float* vsumT = (float*)(wsb + 54528000);             // 128 KB [n][b][d]

    // pass 0: cvt_x folded in; logits == 0 -> uniform c
    wsum0_cvt_k<<<dim3(NCH0, 8), 256, 0, stream>>>(x, W, Wt, xt, sp);
    reduce_k<<<512, 256, 0, stream>>>(sp, vsumT, out, NCH0, 1, 0);
    // pass 1 (fused logits+softmax+wsum, 32x32 MFMA)
    fused_pass_k<<<dim3(NCHF, 2), 512, 0, stream>>>(Wt, xt, vsumT, sp);
    reduce_k<<<512, 256, 0, stream>>>(sp, vsumT, out, NCHF, 0, 0);
    // pass 2
    fused_pass_k<<<dim3(NCHF, 2), 512, 0, stream>>>(Wt, xt, vsumT, sp);
    reduce_k<<<512, 256, 0, stream>>>(sp, vsumT, out, NCHF, 0, 1);
}

// Round 12
// 159.779 us; speedup vs baseline: 1.0245x; 1.0245x over previous
//
#include <hip/hip_runtime.h>
#include <hip/hip_bf16.h>

// Capsule dynamic routing, round 22 = R17 (155.4 us) + ONE change:
// fused pass merges its two 512-thr (bh=0/1) blocks into ONE 1024-thr
// block of 16 waves = (b-half) x (n-group 0..7). Kills the 2x Wt read
// amplification (67 -> 33.5 MB/pass) at identical TLP (1 block/CU x 16
// waves = 4 waves/SIMD, same as 2 blocks x 8 waves).
// R21's cvt_x fold REVERTED (it added 8x-dup xt writes, +8.3 us).
// Counter evidence (R21, first real sighting): wsum0 41.5 us @ 1.46 TB/s
// HBM, ~3.3 TB/s combined R/W -> pipeline is traffic-bound at ~3.3 TB/s
// effective; lever is bytes, not scheduling (explains R14-R17 neutrality).
// Mapping audit (R15 lesson): w=t>>6 in 0..15; bh=w>>3 -> b=bh*32+bc
// covers 0..63; wq=w&7 -> n0=4wq covers all 32 n per bh; psum[p][bh][wq][bc];
// Z sums own-bh 8 wq entries; sp coverage 32n x 64b per chunk. All checked.
//
// x[64][2048][16] f32, W[32][2048][16][16] f32 -> v[64][32][16] f32.
// MFMA layouts (verified): 16x16x32 C/D col=lane&15,row=(lane>>4)*4+reg,
// A[m=lane&15][k=(lane>>4)*8+t]; 32x32x16 C/D col=lane&31,
// row=(reg&3)+8*(reg>>2)+4*(lane>>5), A/B [m|n=lane&31][k=(lane>>5)*8+t].

#define J_DIM 2048
#define NCH0 128           // wsum0 j-chunks (16 j each)
#define NCHF 256           // fused j-chunks (8 j each)

typedef __attribute__((ext_vector_type(8))) short bf16x8;
typedef __attribute__((ext_vector_type(4))) short bf16x4;
typedef __attribute__((ext_vector_type(4))) float f32x4;
typedef __attribute__((ext_vector_type(16))) float f32x16;

__device__ inline float bf2f(short s) {
    union { unsigned u; float f; } v; v.u = ((unsigned)(unsigned short)s) << 16;
    return v.f;
}
// packed f32x2 -> bf16x2 (RNE)
__device__ inline int cvt_pk_bf16(float lo, float hi) {
    int r;
    asm("v_cvt_pk_bf16_f32 %0, %1, %2" : "=v"(r) : "v"(lo), "v"(hi));
    return r;
}
// Barrier WITHOUT the vmcnt(0) drain (R16-validated; intra-block LDS only).
__device__ inline void lds_barrier() {
    __builtin_amdgcn_sched_barrier(0);
    asm volatile("s_waitcnt lgkmcnt(0)" ::: "memory");
    __builtin_amdgcn_sched_barrier(0);
    __builtin_amdgcn_s_barrier();
    __builtin_amdgcn_sched_barrier(0);
}

// x[b][j][16] f32 -> xt[j][b][16] bf16. One thread per (b,j) row.
__global__ __launch_bounds__(256)
void cvt_x_t(const float* __restrict__ x, short* __restrict__ xt) {
    const int id = blockIdx.x * 256 + threadIdx.x;   // j fast for coalesced reads
    const int j = id & (J_DIM - 1), b = id >> 11;
    const float4* s = (const float4*)(x + ((size_t)b * J_DIM + j) * 16);
    float4 q0 = s[0], q1 = s[1], q2 = s[2], q3 = s[3];
    int pk[8];
    pk[0] = cvt_pk_bf16(q0.x, q0.y); pk[1] = cvt_pk_bf16(q0.z, q0.w);
    pk[2] = cvt_pk_bf16(q1.x, q1.y); pk[3] = cvt_pk_bf16(q1.z, q1.w);
    pk[4] = cvt_pk_bf16(q2.x, q2.y); pk[5] = cvt_pk_bf16(q2.z, q2.w);
    pk[6] = cvt_pk_bf16(q3.x, q3.y); pk[7] = cvt_pk_bf16(q3.z, q3.w);
    short* d = xt + ((size_t)j * 64 + b) * 16;
    *(bf16x8*)d = *(bf16x8*)pk;
    *(bf16x8*)(d + 8) = *(bf16x8*)&pk[8 - 4];
}

// Pass 0: read W f32 once (coalesced 1KB-row bursts), convert, write
// Wt[j][n][256] bf16, accumulate UNSCALED uniform-c partials (1/32 applied
// in reduce_k is_first). grid(NCH0, 8) x 256 thr.
__global__ __launch_bounds__(256)
void wsum0_cvt_k(const float* __restrict__ W, short* __restrict__ Wt,
                 const short* __restrict__ xt, short* __restrict__ sp) {
    const int t = threadIdx.x, lane = t & 63, w = t >> 6;
    const int col = lane & 15, g = lane >> 4;
    const int n = blockIdx.y * 4 + w;
    const int chunk = blockIdx.x;

    f32x4 acc[4];
#pragma unroll
    for (int bt = 0; bt < 4; ++bt) acc[bt] = (f32x4){0.f, 0.f, 0.f, 0.f};

#pragma unroll
    for (int jp = 0; jp < 8; ++jp) {
        const int jq = chunk * 16 + jp * 2 + (g >> 1);
        // lane's 8 f32 of W[n][jq] row; half-wave covers the full 1KB row
        const float4* wsrc = (const float4*)(W + ((size_t)n * J_DIM + jq) * 256 + col * 16 + (g & 1) * 8);
        float4 a = wsrc[0], b2 = wsrc[1];
        int pk[4];
        pk[0] = cvt_pk_bf16(a.x, a.y);   pk[1] = cvt_pk_bf16(a.z, a.w);
        pk[2] = cvt_pk_bf16(b2.x, b2.y); pk[3] = cvt_pk_bf16(b2.z, b2.w);
        bf16x8 af = *(bf16x8*)pk;
        *(bf16x8*)(Wt + ((size_t)jq * 32 + n) * 256 + col * 16 + (g & 1) * 8) = af;
#pragma unroll
        for (int bt = 0; bt < 4; ++bt) {
            const int b = bt * 16 + col;
            bf16x8 xr = *(const bf16x8*)(xt + ((size_t)jq * 64 + b) * 16 + (g & 1) * 8);
            acc[bt] = __builtin_amdgcn_mfma_f32_16x16x32_bf16(af, xr, acc[bt], 0, 0, 0);
        }
    }
#pragma unroll
    for (int bt = 0; bt < 4; ++bt) {
        int o[2] = { cvt_pk_bf16(acc[bt][0], acc[bt][1]),
                     cvt_pk_bf16(acc[bt][2], acc[bt][3]) };
        *(bf16x4*)(sp + (((size_t)chunk * 32 + n) * 64 + bt * 16 + col) * 16 + g * 4) = *(bf16x4*)o;
    }
}

// Fused routing pass (32x32x16 MFMA): sp[chunk][n][b][d] = sum_{j in chunk}
// softmax_n(v.u_hat) * u_hat. grid(NCHF) x 1024 thr; 16 waves =
// (bh = w>>3) x (n-group wq = w&7). One block owns all 64 b -> Wt slab read
// ONCE per chunk per pass (33.5 MB, was 67). lane: b-col = lane&31, h=lane>>5.
__global__ __launch_bounds__(1024, 4)
void fused_pass_k(const short* __restrict__ Wt, const short* __restrict__ xt,
                  const float* __restrict__ vsumT, short* __restrict__ sp) {
    const int t = threadIdx.x, lane = t & 63, w = t >> 6;   // w 0..15
    const int bc = lane & 31, h = lane >> 5;
    const int chunk = blockIdx.x;          // 8-j chunk
    const int bh = w >> 3;                 // b-half (in-wave now)
    const int wq = w & 7;                  // n-group
    const int b = bh * 32 + bc;
    const int n0 = wq * 4;

    // A-row role of this lane: m = lane&31 -> (pair-sub n, d)
    const int nsub = bc >> 4;              // 0: lo n of pair, 1: hi n
    const int ad = bc & 15;                // d of the A row

    __shared__ float psum[2][2][8][32];    // [parity][bh][wq][b-col]

    // per-lane slice of vsumT[n0+q][b][d], d in {0..3}+4h and {8..11}+4h
    float4 vvA[4], vvB[4];
#pragma unroll
    for (int q = 0; q < 4; ++q) {
        const float* vp = vsumT + ((size_t)(n0 + q) * 64 + b) * 16;
        vvA[q] = *(const float4*)(vp + 4 * h);
        vvB[q] = *(const float4*)(vp + 8 + 4 * h);
    }

    const f32x16 z16 = {0.f,0.f,0.f,0.f,0.f,0.f,0.f,0.f,
                        0.f,0.f,0.f,0.f,0.f,0.f,0.f,0.f};
    f32x16 acc0 = z16, acc1 = z16;

#pragma unroll 1
    for (int jj = 0; jj < 8; ++jj) {
        const int j = chunk * 8 + jj;
        // B: x[b][j][k], k = h*8+t (full K=16, no masking)
        const bf16x8 xb = *(const bf16x8*)(xt + ((size_t)j * 64 + b) * 16 + h * 8);
        // A: rows = (n-pair, d); lane loads Wt[j][n0+2p+nsub][ad*16 + h*8]
        const bf16x8 af0 = *(const bf16x8*)(Wt + ((size_t)j * 32 + n0 + nsub) * 256 + ad * 16 + h * 8);
        const bf16x8 af1 = *(const bf16x8*)(Wt + ((size_t)j * 32 + n0 + 2 + nsub) * 256 + ad * 16 + h * 8);

        f32x16 u0 = __builtin_amdgcn_mfma_f32_32x32x16_bf16(af0, xb, z16, 0, 0, 0);
        f32x16 u1 = __builtin_amdgcn_mfma_f32_32x32x16_bf16(af1, xb, z16, 0, 0, 0);

        // logits: lane's half-dot over its 8 d's, then combine halves
        float lp0 = vvA[0].x*u0[0] + vvA[0].y*u0[1] + vvA[0].z*u0[2] + vvA[0].w*u0[3]
                  + vvB[0].x*u0[4] + vvB[0].y*u0[5] + vvB[0].z*u0[6] + vvB[0].w*u0[7];
        float lp1 = vvA[1].x*u0[8] + vvA[1].y*u0[9] + vvA[1].z*u0[10] + vvA[1].w*u0[11]
                  + vvB[1].x*u0[12] + vvB[1].y*u0[13] + vvB[1].z*u0[14] + vvB[1].w*u0[15];
        float lp2 = vvA[2].x*u1[0] + vvA[2].y*u1[1] + vvA[2].z*u1[2] + vvA[2].w*u1[3]
                  + vvB[2].x*u1[4] + vvB[2].y*u1[5] + vvB[2].z*u1[6] + vvB[2].w*u1[7];
        float lp3 = vvA[3].x*u1[8] + vvA[3].y*u1[9] + vvA[3].z*u1[10] + vvA[3].w*u1[11]
                  + vvB[3].x*u1[12] + vvB[3].y*u1[13] + vvB[3].z*u1[14] + vvB[3].w*u1[15];
        lp0 += __shfl_xor(lp0, 32);
        lp1 += __shfl_xor(lp1, 32);
        lp2 += __shfl_xor(lp2, 32);
        lp3 += __shfl_xor(lp3, 32);
        // no max-sub: |v|2<=0.5 (squash), |u|2<~8 => |logit|<=~4, f32-safe
        const float e0 = __expf(lp0), e1 = __expf(lp1);
        const float e2 = __expf(lp2), e3 = __expf(lp3);

        const int p = jj & 1;              // parity LDS buffer (WAR across j)
        if (h == 0) psum[p][bh][wq][bc] = e0 + e1 + e2 + e3;
        lds_barrier();
        float Z = 0.f;
#pragma unroll
        for (int ww = 0; ww < 8; ++ww) Z += psum[p][bh][ww][bc];
        const float rz = __builtin_amdgcn_rcpf(Z);
        const float c0 = e0 * rz, c1 = e1 * rz, c2 = e2 * rz, c3 = e3 * rz;
#pragma unroll
        for (int r = 0; r < 16; ++r) {
            acc0[r] += (r < 8 ? c0 : c1) * u0[r];
            acc1[r] += (r < 8 ? c2 : c3) * u1[r];
        }
    }

    // epilogue: reg r -> (n, d): regs 0..3 d=4h.., 4..7 d=8+4h.., 8..15 hi n
#pragma unroll
    for (int pair = 0; pair < 2; ++pair) {
        const f32x16 a = pair ? acc1 : acc0;
        const int nb = n0 + 2 * pair;
        short* lo = sp + (((size_t)chunk * 32 + nb) * 64 + b) * 16;
        short* hi = sp + (((size_t)chunk * 32 + nb + 1) * 64 + b) * 16;
        int o[2];
        o[0] = cvt_pk_bf16(a[0], a[1]);  o[1] = cvt_pk_bf16(a[2], a[3]);
        *(bf16x4*)(lo + 4 * h) = *(bf16x4*)o;
        o[0] = cvt_pk_bf16(a[4], a[5]);  o[1] = cvt_pk_bf16(a[6], a[7]);
        *(bf16x4*)(lo + 8 + 4 * h) = *(bf16x4*)o;
        o[0] = cvt_pk_bf16(a[8], a[9]);  o[1] = cvt_pk_bf16(a[10], a[11]);
        *(bf16x4*)(hi + 4 * h) = *(bf16x4*)o;
        o[0] = cvt_pk_bf16(a[12], a[13]); o[1] = cvt_pk_bf16(a[14], a[15]);
        *(bf16x4*)(hi + 8 + 4 * h) = *(bf16x4*)o;
    }
}

// fold nch bf16 chunk partials, squash, update vsumT / write out. wave per (n,b).
// is_first: STORE vsum and apply the uniform-c 1/32 wsum0 does not pre-apply.
__global__ __launch_bounds__(256)
void reduce_k(const short* __restrict__ sp, float* __restrict__ vsumT,
              float* __restrict__ out, int nch, int is_first, int is_last) {
    const int t = threadIdx.x, lane = t & 63, w = t >> 6;
    const int q = blockIdx.x * 4 + w;       // 0..2047
    const int n = q >> 6, b = q & 63;
    const int d4 = lane & 3, ch = lane >> 2;   // ch 0..15

    float4 a = make_float4(0.f, 0.f, 0.f, 0.f);
    for (int m = 0; m < (nch >> 4); ++m) {
        bf16x4 v = *(const bf16x4*)(sp + (((size_t)(ch + 16 * m) * 32 + n) * 64 + b) * 16 + d4 * 4);
        a.x += bf2f(v[0]); a.y += bf2f(v[1]); a.z += bf2f(v[2]); a.w += bf2f(v[3]);
    }
#pragma unroll
    for (int mk = 4; mk <= 32; mk <<= 1) {
        a.x += __shfl_xor(a.x, mk); a.y += __shfl_xor(a.y, mk);
        a.z += __shfl_xor(a.z, mk); a.w += __shfl_xor(a.w, mk);
    }
    const float sc = is_first ? 0.03125f : 1.0f;   // uniform c = 1/32 (pass 0)
    a.x *= sc; a.y *= sc; a.z *= sc; a.w *= sc;
    float tt = a.x * a.x + a.y * a.y + a.z * a.z + a.w * a.w;
    tt += __shfl_xor(tt, 1);
    tt += __shfl_xor(tt, 2);
    float s2 = tt + 1e-7f;
    float scale = sqrtf(s2) / (1.0f + s2);

    if (lane < 4) {
        float4 v = make_float4(a.x * scale, a.y * scale, a.z * scale, a.w * scale);
        if (is_last) {
            *(float4*)(out + ((size_t)b * 32 + n) * 16 + d4 * 4) = v;   // [b][n][d]
        } else {
            float* p = vsumT + ((size_t)n * 64 + b) * 16 + d4 * 4;      // [n][b][d]
            if (is_first) {
                *(float4*)p = v;
            } else {
                float4 o = *(const float4*)p;
                *(float4*)p = make_float4(o.x + v.x, o.y + v.y, o.z + v.z, o.w + v.w);
            }
        }
    }
}

extern "C" void kernel_launch(void* const* d_in, const int* in_sizes, int n_in,
                              void* d_out, int out_size, void* d_ws, size_t ws_size,
                              hipStream_t stream) {
    const float* x = (const float*)d_in[0];   // [64,2048,16]
    const float* W = (const float*)d_in[1];   // [32,2048,16,16]
    float* out = (float*)d_out;               // [64,32,16]

    char* wsb = (char*)d_ws;
    short* Wt    = (short*)(wsb);                        // 33.5 MB [j][n][256]
    short* xt    = (short*)(wsb + 33556480);             // 4.2 MB [j][b][16]
    short* sp    = (short*)(wsb + 37750784);             // 16.78 MB [chunk<=256][n][b][d]
    float* vsumT = (float*)(wsb + 54528000);             // 128 KB [n][b][d]

    cvt_x_t<<<512, 256, 0, stream>>>(x, xt);

    // pass 0: logits == 0 -> uniform c; W converted+transposed in-flight
    wsum0_cvt_k<<<dim3(NCH0, 8), 256, 0, stream>>>(W, Wt, xt, sp);
    reduce_k<<<512, 256, 0, stream>>>(sp, vsumT, out, NCH0, 1, 0);
    // pass 1 (fused logits+softmax+wsum, 32x32 MFMA, 16-wave block)
    fused_pass_k<<<NCHF, 1024, 0, stream>>>(Wt, xt, vsumT, sp);
    reduce_k<<<512, 256, 0, stream>>>(sp, vsumT, out, NCHF, 0, 0);
    // pass 2
    fused_pass_k<<<NCHF, 1024, 0, stream>>>(Wt, xt, vsumT, sp);
    reduce_k<<<512, 256, 0, stream>>>(sp, vsumT, out, NCHF, 0, 1);
}

// Round 13
// 157.097 us; speedup vs baseline: 1.0420x; 1.0171x over previous
//
#include <hip/hip_runtime.h>
#include <hip/hip_bf16.h>

// Capsule dynamic routing, round 23 = R17 (155.4 us, banked best) + ONE
// change: fused pass prefetches j+1's af0/af1 (Wt) across the raw barrier.
// R22 post-mortem: halving fused's Wt traffic REGRESSED (+4.4) -> fused is
// latency-exposed, not BW-bound. R17's fused has NO prefetch; each j opens
// with 2 serial Wt loads (~350-500 cyc L3) gating the MFMAs. The raw
// lds_barrier (lgkmcnt-only, R16-validated) lets loads issued before it
// stay in flight -- untested combination on the 32x32 kernel.
// Register audit: acc 32 + vv 32 + u 32 + cur ops ~20 + prefetch 16 ~= 120
// <= 128 @ launch_bounds(512,4) -> no spill. xb NOT prefetched (xt L2-hot,
// keeps us under the VGPR cliff).
//
// x[64][2048][16] f32, W[32][2048][16][16] f32 -> v[64][32][16] f32.
// MFMA layouts (verified): 16x16x32 C/D col=lane&15,row=(lane>>4)*4+reg,
// A[m=lane&15][k=(lane>>4)*8+t]; 32x32x16 C/D col=lane&31,
// row=(reg&3)+8*(reg>>2)+4*(lane>>5), A/B [m|n=lane&31][k=(lane>>5)*8+t].

#define J_DIM 2048
#define NCH0 128           // wsum0 j-chunks (16 j each)
#define NCHF 256           // fused j-chunks (8 j each)

typedef __attribute__((ext_vector_type(8))) short bf16x8;
typedef __attribute__((ext_vector_type(4))) short bf16x4;
typedef __attribute__((ext_vector_type(4))) float f32x4;
typedef __attribute__((ext_vector_type(16))) float f32x16;

__device__ inline float bf2f(short s) {
    union { unsigned u; float f; } v; v.u = ((unsigned)(unsigned short)s) << 16;
    return v.f;
}
// packed f32x2 -> bf16x2 (RNE)
__device__ inline int cvt_pk_bf16(float lo, float hi) {
    int r;
    asm("v_cvt_pk_bf16_f32 %0, %1, %2" : "=v"(r) : "v"(lo), "v"(hi));
    return r;
}
// Barrier WITHOUT the vmcnt(0) drain (R16-validated; intra-block LDS only).
__device__ inline void lds_barrier() {
    __builtin_amdgcn_sched_barrier(0);
    asm volatile("s_waitcnt lgkmcnt(0)" ::: "memory");
    __builtin_amdgcn_sched_barrier(0);
    __builtin_amdgcn_s_barrier();
    __builtin_amdgcn_sched_barrier(0);
}

// x[b][j][16] f32 -> xt[j][b][16] bf16. One thread per (b,j) row.
__global__ __launch_bounds__(256)
void cvt_x_t(const float* __restrict__ x, short* __restrict__ xt) {
    const int id = blockIdx.x * 256 + threadIdx.x;   // j fast for coalesced reads
    const int j = id & (J_DIM - 1), b = id >> 11;
    const float4* s = (const float4*)(x + ((size_t)b * J_DIM + j) * 16);
    float4 q0 = s[0], q1 = s[1], q2 = s[2], q3 = s[3];
    int pk[8];
    pk[0] = cvt_pk_bf16(q0.x, q0.y); pk[1] = cvt_pk_bf16(q0.z, q0.w);
    pk[2] = cvt_pk_bf16(q1.x, q1.y); pk[3] = cvt_pk_bf16(q1.z, q1.w);
    pk[4] = cvt_pk_bf16(q2.x, q2.y); pk[5] = cvt_pk_bf16(q2.z, q2.w);
    pk[6] = cvt_pk_bf16(q3.x, q3.y); pk[7] = cvt_pk_bf16(q3.z, q3.w);
    short* d = xt + ((size_t)j * 64 + b) * 16;
    *(bf16x8*)d = *(bf16x8*)pk;
    *(bf16x8*)(d + 8) = *(bf16x8*)&pk[4];
}

// Pass 0: read W f32 once (coalesced 1KB-row bursts), convert, write
// Wt[j][n][256] bf16, accumulate UNSCALED uniform-c partials (1/32 applied
// in reduce_k is_first). grid(NCH0, 8) x 256 thr.
__global__ __launch_bounds__(256)
void wsum0_cvt_k(const float* __restrict__ W, short* __restrict__ Wt,
                 const short* __restrict__ xt, short* __restrict__ sp) {
    const int t = threadIdx.x, lane = t & 63, w = t >> 6;
    const int col = lane & 15, g = lane >> 4;
    const int n = blockIdx.y * 4 + w;
    const int chunk = blockIdx.x;

    f32x4 acc[4];
#pragma unroll
    for (int bt = 0; bt < 4; ++bt) acc[bt] = (f32x4){0.f, 0.f, 0.f, 0.f};

#pragma unroll
    for (int jp = 0; jp < 8; ++jp) {
        const int jq = chunk * 16 + jp * 2 + (g >> 1);
        // lane's 8 f32 of W[n][jq] row; half-wave covers the full 1KB row
        const float4* wsrc = (const float4*)(W + ((size_t)n * J_DIM + jq) * 256 + col * 16 + (g & 1) * 8);
        float4 a = wsrc[0], b2 = wsrc[1];
        int pk[4];
        pk[0] = cvt_pk_bf16(a.x, a.y);   pk[1] = cvt_pk_bf16(a.z, a.w);
        pk[2] = cvt_pk_bf16(b2.x, b2.y); pk[3] = cvt_pk_bf16(b2.z, b2.w);
        bf16x8 af = *(bf16x8*)pk;
        *(bf16x8*)(Wt + ((size_t)jq * 32 + n) * 256 + col * 16 + (g & 1) * 8) = af;
#pragma unroll
        for (int bt = 0; bt < 4; ++bt) {
            const int b = bt * 16 + col;
            bf16x8 xr = *(const bf16x8*)(xt + ((size_t)jq * 64 + b) * 16 + (g & 1) * 8);
            acc[bt] = __builtin_amdgcn_mfma_f32_16x16x32_bf16(af, xr, acc[bt], 0, 0, 0);
        }
    }
#pragma unroll
    for (int bt = 0; bt < 4; ++bt) {
        int o[2] = { cvt_pk_bf16(acc[bt][0], acc[bt][1]),
                     cvt_pk_bf16(acc[bt][2], acc[bt][3]) };
        *(bf16x4*)(sp + (((size_t)chunk * 32 + n) * 64 + bt * 16 + col) * 16 + g * 4) = *(bf16x4*)o;
    }
}

// Fused routing pass (32x32x16 MFMA): sp[chunk][n][b][d] = sum_{j in chunk}
// softmax_n(v.u_hat) * u_hat for one 32-b half. grid(NCHF, 2) x 512 thr.
// wave w = n-group {4w..4w+3}; lane: b-col = lane&31, half h = lane>>5.
// NEW: af0/af1 for j+1 issued before the barrier; raw lds_barrier keeps
// them in flight through the softmax exchange.
__global__ __launch_bounds__(512, 4)
void fused_pass_k(const short* __restrict__ Wt, const short* __restrict__ xt,
                  const float* __restrict__ vsumT, short* __restrict__ sp) {
    const int t = threadIdx.x, lane = t & 63, w = t >> 6;   // w 0..7: n-group
    const int bc = lane & 31, h = lane >> 5;
    const int chunk = blockIdx.x;          // 8-j chunk
    const int bh = blockIdx.y;             // b-half
    const int b = bh * 32 + bc;
    const int n0 = w * 4;

    // A-row role of this lane: m = lane&31 -> (pair-sub n, d)
    const int nsub = bc >> 4;              // 0: lo n of pair, 1: hi n
    const int ad = bc & 15;                // d of the A row

    __shared__ float psum[2][8][32];       // [parity][wave][b-col]

    // per-lane slice of vsumT[n0+q][b][d], d in {0..3}+4h and {8..11}+4h
    float4 vvA[4], vvB[4];
#pragma unroll
    for (int q = 0; q < 4; ++q) {
        const float* vp = vsumT + ((size_t)(n0 + q) * 64 + b) * 16;
        vvA[q] = *(const float4*)(vp + 4 * h);
        vvB[q] = *(const float4*)(vp + 8 + 4 * h);
    }

    const f32x16 z16 = {0.f,0.f,0.f,0.f,0.f,0.f,0.f,0.f,
                        0.f,0.f,0.f,0.f,0.f,0.f,0.f,0.f};
    f32x16 acc0 = z16, acc1 = z16;

    // prefetch stage: af rows for j = chunk*8
    const size_t aoff = (size_t)ad * 16 + h * 8;
    bf16x8 af0_n = *(const bf16x8*)(Wt + ((size_t)(chunk * 8) * 32 + n0 + nsub) * 256 + aoff);
    bf16x8 af1_n = *(const bf16x8*)(Wt + ((size_t)(chunk * 8) * 32 + n0 + 2 + nsub) * 256 + aoff);

#pragma unroll 1
    for (int jj = 0; jj < 8; ++jj) {
        const int j = chunk * 8 + jj;
        // consume staged A operands
        const bf16x8 af0 = af0_n;
        const bf16x8 af1 = af1_n;
        // B: x[b][j][k], k = h*8+t (full K=16, no masking); L2-hot, no prefetch
        const bf16x8 xb = *(const bf16x8*)(xt + ((size_t)j * 64 + b) * 16 + h * 8);

        // issue j+1's af loads NOW -- in flight across the raw barrier below
        if (jj < 7) {
            af0_n = *(const bf16x8*)(Wt + ((size_t)(j + 1) * 32 + n0 + nsub) * 256 + aoff);
            af1_n = *(const bf16x8*)(Wt + ((size_t)(j + 1) * 32 + n0 + 2 + nsub) * 256 + aoff);
        }

        f32x16 u0 = __builtin_amdgcn_mfma_f32_32x32x16_bf16(af0, xb, z16, 0, 0, 0);
        f32x16 u1 = __builtin_amdgcn_mfma_f32_32x32x16_bf16(af1, xb, z16, 0, 0, 0);

        // logits: lane's half-dot over its 8 d's, then combine halves
        float lp0 = vvA[0].x*u0[0] + vvA[0].y*u0[1] + vvA[0].z*u0[2] + vvA[0].w*u0[3]
                  + vvB[0].x*u0[4] + vvB[0].y*u0[5] + vvB[0].z*u0[6] + vvB[0].w*u0[7];
        float lp1 = vvA[1].x*u0[8] + vvA[1].y*u0[9] + vvA[1].z*u0[10] + vvA[1].w*u0[11]
                  + vvB[1].x*u0[12] + vvB[1].y*u0[13] + vvB[1].z*u0[14] + vvB[1].w*u0[15];
        float lp2 = vvA[2].x*u1[0] + vvA[2].y*u1[1] + vvA[2].z*u1[2] + vvA[2].w*u1[3]
                  + vvB[2].x*u1[4] + vvB[2].y*u1[5] + vvB[2].z*u1[6] + vvB[2].w*u1[7];
        float lp3 = vvA[3].x*u1[8] + vvA[3].y*u1[9] + vvA[3].z*u1[10] + vvA[3].w*u1[11]
                  + vvB[3].x*u1[12] + vvB[3].y*u1[13] + vvB[3].z*u1[14] + vvB[3].w*u1[15];
        lp0 += __shfl_xor(lp0, 32);
        lp1 += __shfl_xor(lp1, 32);
        lp2 += __shfl_xor(lp2, 32);
        lp3 += __shfl_xor(lp3, 32);
        // no max-sub: |v|2<=0.5 (squash), |u|2<~8 => |logit|<=~4, f32-safe
        const float e0 = __expf(lp0), e1 = __expf(lp1);
        const float e2 = __expf(lp2), e3 = __expf(lp3);

        const int p = jj & 1;              // parity LDS buffer (WAR across j)
        if (h == 0) psum[p][w][bc] = e0 + e1 + e2 + e3;
        lds_barrier();
        float Z = 0.f;
#pragma unroll
        for (int ww = 0; ww < 8; ++ww) Z += psum[p][ww][bc];
        const float rz = __builtin_amdgcn_rcpf(Z);
        const float c0 = e0 * rz, c1 = e1 * rz, c2 = e2 * rz, c3 = e3 * rz;
#pragma unroll
        for (int r = 0; r < 16; ++r) {
            acc0[r] += (r < 8 ? c0 : c1) * u0[r];
            acc1[r] += (r < 8 ? c2 : c3) * u1[r];
        }
    }

    // epilogue: reg r -> (n, d): regs 0..3 d=4h.., 4..7 d=8+4h.., 8..15 hi n
#pragma unroll
    for (int pair = 0; pair < 2; ++pair) {
        const f32x16 a = pair ? acc1 : acc0;
        const int nb = n0 + 2 * pair;
        short* lo = sp + (((size_t)chunk * 32 + nb) * 64 + b) * 16;
        short* hi = sp + (((size_t)chunk * 32 + nb + 1) * 64 + b) * 16;
        int o[2];
        o[0] = cvt_pk_bf16(a[0], a[1]);  o[1] = cvt_pk_bf16(a[2], a[3]);
        *(bf16x4*)(lo + 4 * h) = *(bf16x4*)o;
        o[0] = cvt_pk_bf16(a[4], a[5]);  o[1] = cvt_pk_bf16(a[6], a[7]);
        *(bf16x4*)(lo + 8 + 4 * h) = *(bf16x4*)o;
        o[0] = cvt_pk_bf16(a[8], a[9]);  o[1] = cvt_pk_bf16(a[10], a[11]);
        *(bf16x4*)(hi + 4 * h) = *(bf16x4*)o;
        o[0] = cvt_pk_bf16(a[12], a[13]); o[1] = cvt_pk_bf16(a[14], a[15]);
        *(bf16x4*)(hi + 8 + 4 * h) = *(bf16x4*)o;
    }
}

// fold nch bf16 chunk partials, squash, update vsumT / write out. wave per (n,b).
// is_first: STORE vsum and apply the uniform-c 1/32 wsum0 does not pre-apply.
__global__ __launch_bounds__(256)
void reduce_k(const short* __restrict__ sp, float* __restrict__ vsumT,
              float* __restrict__ out, int nch, int is_first, int is_last) {
    const int t = threadIdx.x, lane = t & 63, w = t >> 6;
    const int q = blockIdx.x * 4 + w;       // 0..2047
    const int n = q >> 6, b = q & 63;
    const int d4 = lane & 3, ch = lane >> 2;   // ch 0..15

    float4 a = make_float4(0.f, 0.f, 0.f, 0.f);
    for (int m = 0; m < (nch >> 4); ++m) {
        bf16x4 v = *(const bf16x4*)(sp + (((size_t)(ch + 16 * m) * 32 + n) * 64 + b) * 16 + d4 * 4);
        a.x += bf2f(v[0]); a.y += bf2f(v[1]); a.z += bf2f(v[2]); a.w += bf2f(v[3]);
    }
#pragma unroll
    for (int mk = 4; mk <= 32; mk <<= 1) {
        a.x += __shfl_xor(a.x, mk); a.y += __shfl_xor(a.y, mk);
        a.z += __shfl_xor(a.z, mk); a.w += __shfl_xor(a.w, mk);
    }
    const float sc = is_first ? 0.03125f : 1.0f;   // uniform c = 1/32 (pass 0)
    a.x *= sc; a.y *= sc; a.z *= sc; a.w *= sc;
    float tt = a.x * a.x + a.y * a.y + a.z * a.z + a.w * a.w;
    tt += __shfl_xor(tt, 1);
    tt += __shfl_xor(tt, 2);
    float s2 = tt + 1e-7f;
    float scale = sqrtf(s2) / (1.0f + s2);

    if (lane < 4) {
        float4 v = make_float4(a.x * scale, a.y * scale, a.z * scale, a.w * scale);
        if (is_last) {
            *(float4*)(out + ((size_t)b * 32 + n) * 16 + d4 * 4) = v;   // [b][n][d]
        } else {
            float* p = vsumT + ((size_t)n * 64 + b) * 16 + d4 * 4;      // [n][b][d]
            if (is_first) {
                *(float4*)p = v;
            } else {
                float4 o = *(const float4*)p;
                *(float4*)p = make_float4(o.x + v.x, o.y + v.y, o.z + v.z, o.w + v.w);
            }
        }
    }
}

extern "C" void kernel_launch(void* const* d_in, const int* in_sizes, int n_in,
                              void* d_out, int out_size, void* d_ws, size_t ws_size,
                              hipStream_t stream) {
    const float* x = (const float*)d_in[0];   // [64,2048,16]
    const float* W = (const float*)d_in[1];   // [32,2048,16,16]
    float* out = (float*)d_out;               // [64,32,16]

    char* wsb = (char*)d_ws;
    short* Wt    = (short*)(wsb);                        // 33.5 MB [j][n][256]
    short* xt    = (short*)(wsb + 33556480);             // 4.2 MB [j][b][16]
    short* sp    = (short*)(wsb + 37750784);             // 16.78 MB [chunk<=256][n][b][d]
    float* vsumT = (float*)(wsb + 54528000);             // 128 KB [n][b][d]

    cvt_x_t<<<512, 256, 0, stream>>>(x, xt);

    // pass 0: logits == 0 -> uniform c; W converted+transposed in-flight
    wsum0_cvt_k<<<dim3(NCH0, 8), 256, 0, stream>>>(W, Wt, xt, sp);
    reduce_k<<<512, 256, 0, stream>>>(sp, vsumT, out, NCH0, 1, 0);
    // pass 1 (fused logits+softmax+wsum, 32x32 MFMA, af-prefetch)
    fused_pass_k<<<dim3(NCHF, 2), 512, 0, stream>>>(Wt, xt, vsumT, sp);
    reduce_k<<<512, 256, 0, stream>>>(sp, vsumT, out, NCHF, 0, 0);
    // pass 2
    fused_pass_k<<<dim3(NCHF, 2), 512, 0, stream>>>(Wt, xt, vsumT, sp);
    reduce_k<<<512, 256, 0, stream>>>(sp, vsumT, out, NCHF, 0, 1);
}